// Round 3
// baseline (33232.538 us; speedup 1.0000x reference)
//
#include <hip/hip_runtime.h>
#include <cstdint>
#include <cstddef>

// ---------------------------------------------------------------------------
// 3-layer LSTMP, folded-projection formulation — PER-STEP LAUNCH version.
//   u_t = o*tanh(c);  gates_t = in_t@Wx + u_{t-1}@(Wp@Wh) + b
//   inter-layer seq = h_t = u_t@Wp (lagged by one launch)
//   layer carry: c via global C buffer; h via xg0b = h_final @ Wh_next
//   final: relu((sum_t u2)/400 @Wp2 @ W^T + lb), L2-normalized.
// No cross-WG sync inside any launch: stream order is the only dependency.
// R2 fix: Ut->U copy was moving 2048 of 4096 bytes (f32x4 = 8 shorts, not 16).
// ---------------------------------------------------------------------------

typedef __attribute__((ext_vector_type(8))) short bf16x8;
typedef __attribute__((ext_vector_type(4))) float f32x4;

#define TT 400
#define NB 256
#define IIP 96     // input dim 80 padded to 96 (3 K-chunks of 32)
#define HH 768
#define PP 256
#define G4 3072

__device__ __forceinline__ short f2bf(float f) {
  unsigned u = __builtin_bit_cast(unsigned, f);
  unsigned r = u + 0x7FFFu + ((u >> 16) & 1u);
  return (short)(r >> 16);
}
__device__ __forceinline__ float sigf(float x) { return 1.0f / (1.0f + __expf(-x)); }
__device__ __forceinline__ float tanh_(float x) { return 1.0f - 2.0f / (__expf(2.0f * x) + 1.0f); }

// --------------------------- prep kernels ----------------------------------

__global__ void k_xb(const float* __restrict__ x, short* __restrict__ xb) {
  int idx = blockIdx.x * 256 + threadIdx.x;
  if (idx >= TT * NB * 80) return;
  int i = idx % 80, tb = idx / 80;
  int b = tb % NB, t = tb / NB;
  xb[(size_t)(t * NB + b) * IIP + i] = f2bf(x[(size_t)(b * TT + t) * 80 + i]);
}

// B_l[n'][k] (bf16, transposed, gate-permuted): k<KIN -> Wx direct (pad 0),
// k>=KIN -> (Wp@Wh)[k-KIN][col]   ; col(n') = (tl&3)*768 + jj*32 + (tl>>2)*16 + cc
__global__ void k_makeB(const float* __restrict__ Wx, const float* __restrict__ Wp,
                        const float* __restrict__ Wh, short* __restrict__ out,
                        int K, int KIN, int INDIM) {
  int np = blockIdx.x * 256 + threadIdx.x;
  int k = blockIdx.y;
  int tl = (np >> 4) & 7, cc = np & 15, jj = np >> 7;
  int col = (tl & 3) * HH + jj * 32 + (tl >> 2) * 16 + cc;
  float v;
  if (k < KIN) {
    v = (k < INDIM) ? Wx[(size_t)k * G4 + col] : 0.0f;
  } else {
    float a = 0.f;
    int kr = k - KIN;
    for (int q = 0; q < PP; ++q)
      a = fmaf(Wp[(size_t)kr * PP + q], Wh[(size_t)q * G4 + col], a);
    v = a;
  }
  out[(size_t)np * K + k] = f2bf(v);
}

__global__ void k_wpT(const float* __restrict__ Wp, short* __restrict__ WpT) {
  int idx = blockIdx.x * 256 + threadIdx.x;
  if (idx >= PP * HH) return;
  int n = idx % PP, k = idx / PP;
  WpT[(size_t)n * HH + k] = f2bf(Wp[(size_t)k * PP + n]);
}

__global__ void k_whT(const float* __restrict__ Wh, short* __restrict__ WhT) {
  int idx = blockIdx.x * 256 + threadIdx.x;
  if (idx >= G4 * PP) return;
  int np = idx % G4, k = idx / G4;
  int tl = (np >> 4) & 7, cc = np & 15, jj = np >> 7;
  int col = (tl & 3) * HH + jj * 32 + (tl >> 2) * 16 + cc;
  WhT[(size_t)np * PP + k] = f2bf(Wh[(size_t)k * G4 + col]);
}

__global__ void k_pb(const float* b0, const float* b1, const float* b2, float* pb) {
  int n = blockIdx.x * 256 + threadIdx.x;
  if (n >= 3 * G4) return;
  int l = n / G4, np = n % G4;
  int tl = (np >> 4) & 7, cc = np & 15, jj = np >> 7;
  int col = (tl & 3) * HH + jj * 32 + (tl >> 2) * 16 + cc;
  pb[n] = (l == 0 ? b0 : (l == 1 ? b1 : b2))[col];
}

__global__ void k_wt(const float* __restrict__ W, float* __restrict__ Wt) {
  int idx = blockIdx.x * 256 + threadIdx.x;
  int q = idx >> 8, p = idx & 255;
  Wt[idx] = W[p * 256 + q];
}

// --------------------------- per-step kernel -------------------------------
// grid 96 = 4 batch-groups (blk&3, 64 rows) x 24 col-blocks (blk>>2, 128 gate cols)

template <int K, int CIN>
__global__ void __launch_bounds__(256) k_step(
    const short* __restrict__ Bw,
    const short* __restrict__ inS, int inStr,
    const short* __restrict__ WpT, short* __restrict__ projOut,
    const float* __restrict__ pbL,
    short* __restrict__ U, float* __restrict__ C,
    float* __restrict__ S, const float* __restrict__ xg0b,
    int t, int useXg, int doSum)
{
  const int blk = blockIdx.x;
  const int g = blk & 3;
  const int j = blk >> 2;
  const int tid = threadIdx.x;
  const int lane = tid & 63;
  const int wv = tid >> 6;
  const int mv = wv >> 1;
  const int nv = wv & 1;
  const int c0 = lane & 15;
  const int rg = lane >> 4;
  const int row0 = g * 64;
  constexpr int NC = K >> 5;

  __shared__ alignas(16) short Ut[64 * 32];

  // ---------------- gates + cell update (time t) ----------------
  if (t < TT) {
    const int pw = t & 1, pr = pw ^ 1;
    const short* arow_in = inS + (size_t)t * NB * inStr + (size_t)row0 * inStr;
    const short* arow_u  = U + (size_t)pr * NB * HH + (size_t)row0 * HH;
    const bool skipU = (t == 0);

    f32x4 acc[2][4];
    if (t == 0 && useXg) {
      #pragma unroll
      for (int mt = 0; mt < 2; ++mt)
        #pragma unroll
        for (int nt = 0; nt < 4; ++nt)
          #pragma unroll
          for (int r = 0; r < 4; ++r)
            acc[mt][nt][r] = xg0b[(size_t)(row0 + mv * 32 + mt * 16 + rg * 4 + r) * G4
                                  + j * 128 + (nv * 4 + nt) * 16 + c0];
    } else {
      f32x4 zz = {0.f, 0.f, 0.f, 0.f};
      #pragma unroll
      for (int mt = 0; mt < 2; ++mt)
        #pragma unroll
        for (int nt = 0; nt < 4; ++nt)
          acc[mt][nt] = zz;
    }

    float bias[4];
    #pragma unroll
    for (int q = 0; q < 4; ++q)
      bias[q] = pbL[j * 128 + (nv * 4 + q) * 16 + c0];

    const short* bbase[4];
    #pragma unroll
    for (int nt = 0; nt < 4; ++nt)
      bbase[nt] = Bw + (size_t)(j * 128 + (nv * 4 + nt) * 16 + c0) * K + rg * 8;

    bf16x8 fa[2][2], fb[2][4];
    auto loadC = [&](int buf, int c) {
      bf16x8 bz = {0, 0, 0, 0, 0, 0, 0, 0};
      #pragma unroll
      for (int mt = 0; mt < 2; ++mt) {
        int rr = mv * 32 + mt * 16 + c0;
        bf16x8 v = bz;
        if (c < CIN)       v = *(const bf16x8*)(arow_in + (size_t)rr * inStr + c * 32 + rg * 8);
        else if (!skipU)   v = *(const bf16x8*)(arow_u + (size_t)rr * HH + (c - CIN) * 32 + rg * 8);
        fa[buf][mt] = v;
      }
      #pragma unroll
      for (int nt = 0; nt < 4; ++nt)
        fb[buf][nt] = *(const bf16x8*)(bbase[nt] + c * 32);
    };
    auto mmaC = [&](int buf) {
      #pragma unroll
      for (int mt = 0; mt < 2; ++mt)
        #pragma unroll
        for (int nt = 0; nt < 4; ++nt)
          acc[mt][nt] = __builtin_amdgcn_mfma_f32_16x16x32_bf16(fa[buf][mt], fb[buf][nt], acc[mt][nt], 0, 0, 0);
    };

    loadC(0, 0);
    loadC(1, 1);
    for (int c = 0; c < NC; c += 2) {
      mmaC(0);
      if (c + 2 < NC) loadC(0, c + 2);
      if (c + 1 < NC) { mmaC(1); if (c + 3 < NC) loadC(1, c + 3); }
    }

    #pragma unroll
    for (int mt = 0; mt < 2; ++mt) {
      #pragma unroll
      for (int r = 0; r < 4; ++r) {
        int rl = mv * 32 + mt * 16 + rg * 4 + r;
        size_t cidx = (size_t)(row0 + rl) * HH + j * 32 + nv * 16 + c0;
        float gi = acc[mt][0][r] + bias[0];
        float gf = acc[mt][1][r] + bias[1];
        float gg = acc[mt][2][r] + bias[2];
        float go = acc[mt][3][r] + bias[3];
        float cprev = C[cidx];
        float cc2 = sigf(gf) * cprev + sigf(gi) * tanh_(gg);
        C[cidx] = cc2;
        float uu = sigf(go) * tanh_(cc2);
        if (doSum) S[cidx] += uu;
        Ut[rl * 32 + nv * 16 + c0] = f2bf(uu);
      }
    }
    __syncthreads();
    {
      // full 4096-byte copy: 256 threads x 16B (f32x4 = 8 shorts)
      int rl = tid >> 2, q = tid & 3;
      f32x4 v = *(const f32x4*)(Ut + rl * 32 + q * 8);
      *(f32x4*)(U + (size_t)pw * NB * HH + (size_t)(row0 + rl) * HH + j * 32 + q * 8) = v;
    }
  }

  // ---------------- lagged projection h_{t-1} = u_{t-1}@Wp ----------------
  if (projOut != nullptr && j < 16 && t >= 1) {
    const int tp = t - 1;
    const int pu = tp & 1;
    const short* au = U + (size_t)pu * NB * HH + (size_t)(row0 + wv * 16) * HH;
    const short* wb = WpT + (size_t)(j * 16 + c0) * HH + rg * 8;
    f32x4 pacc = {0.f, 0.f, 0.f, 0.f};
    #pragma unroll 4
    for (int c = 0; c < 24; ++c) {
      bf16x8 a = *(const bf16x8*)(au + (size_t)c0 * HH + c * 32 + rg * 8);
      bf16x8 b = *(const bf16x8*)(wb + c * 32);
      pacc = __builtin_amdgcn_mfma_f32_16x16x32_bf16(a, b, pacc, 0, 0, 0);
    }
    #pragma unroll
    for (int r = 0; r < 4; ++r) {
      int rr = row0 + wv * 16 + rg * 4 + r;
      projOut[(size_t)tp * NB * PP + (size_t)rr * PP + j * 16 + c0] = f2bf(pacc[r]);
    }
  }
}

// --------------- layer transition: xg0b = h_final @ Wh_next ----------------

__global__ void __launch_bounds__(256) k_trans(
    const short* __restrict__ seqF,   // seqH + 399*NB*PP
    const short* __restrict__ WhT, float* __restrict__ xg0b)
{
  const int blk = blockIdx.x;
  const int g = blk & 3, j = blk >> 2;
  const int tid = threadIdx.x, lane = tid & 63, wv = tid >> 6;
  const int mv = wv >> 1, nv = wv & 1, c0 = lane & 15, rg = lane >> 4;
  const int row0 = g * 64;
  const short* aseq = seqF + (size_t)row0 * PP;

  f32x4 zz = {0.f, 0.f, 0.f, 0.f};
  f32x4 xacc[2][4];
  #pragma unroll
  for (int mt = 0; mt < 2; ++mt)
    #pragma unroll
    for (int nt = 0; nt < 4; ++nt)
      xacc[mt][nt] = zz;
  #pragma unroll
  for (int c = 0; c < 8; ++c) {
    bf16x8 a2[2];
    #pragma unroll
    for (int mt = 0; mt < 2; ++mt)
      a2[mt] = *(const bf16x8*)(aseq + (size_t)(mv * 32 + mt * 16 + c0) * PP + c * 32 + rg * 8);
    #pragma unroll
    for (int nt = 0; nt < 4; ++nt) {
      bf16x8 b2 = *(const bf16x8*)(WhT + (size_t)(j * 128 + (nv * 4 + nt) * 16 + c0) * PP + c * 32 + rg * 8);
      #pragma unroll
      for (int mt = 0; mt < 2; ++mt)
        xacc[mt][nt] = __builtin_amdgcn_mfma_f32_16x16x32_bf16(a2[mt], b2, xacc[mt][nt], 0, 0, 0);
    }
  }
  #pragma unroll
  for (int mt = 0; mt < 2; ++mt)
    #pragma unroll
    for (int nt = 0; nt < 4; ++nt)
      #pragma unroll
      for (int r = 0; r < 4; ++r)
        xg0b[(size_t)(row0 + mv * 32 + mt * 16 + rg * 4 + r) * G4
             + j * 128 + (nv * 4 + nt) * 16 + c0] = xacc[mt][nt][r];
}

// --------------------------- epilogue --------------------------------------

__global__ void k_mh(const float* __restrict__ S, const float* __restrict__ Wp2, float* __restrict__ mh) {
  __shared__ float sl[HH];
  int b = blockIdx.x, p = threadIdx.x;
  for (int i = p; i < HH; i += 256) sl[i] = S[(size_t)b * HH + i] * (1.0f / 400.0f);
  __syncthreads();
  float a = 0.f;
  for (int k = 0; k < HH; ++k) a = fmaf(sl[k], Wp2[(size_t)k * PP + p], a);
  mh[b * PP + p] = a;
}

__global__ void k_out(const float* __restrict__ mh, const float* __restrict__ Wt,
                      const float* __restrict__ lb, float* __restrict__ out) {
  __shared__ float ml[PP];
  __shared__ float red[PP];
  int b = blockIdx.x, p = threadIdx.x;
  ml[p] = mh[b * PP + p];
  __syncthreads();
  float z = lb[p];
  for (int q = 0; q < PP; ++q) z = fmaf(ml[q], Wt[q * PP + p], z);
  z = fmaxf(z, 0.0f);
  red[p] = z * z;
  __syncthreads();
  for (int st = 128; st > 0; st >>= 1) { if (p < st) red[p] += red[p + st]; __syncthreads(); }
  out[b * PP + p] = z / sqrtf(red[0]);
}

// --------------------------- launch ----------------------------------------

extern "C" void kernel_launch(void* const* d_in, const int* in_sizes, int n_in,
                              void* d_out, int out_size, void* d_ws, size_t ws_size,
                              hipStream_t stream) {
  (void)in_sizes; (void)n_in; (void)out_size; (void)ws_size;
  const float* x   = (const float*)d_in[0];
  const float* Wx0 = (const float*)d_in[1];
  const float* Wh0 = (const float*)d_in[2];
  const float* b0  = (const float*)d_in[3];
  const float* Wp0 = (const float*)d_in[4];
  const float* Wx1 = (const float*)d_in[5];
  const float* Wh1 = (const float*)d_in[6];
  const float* b1  = (const float*)d_in[7];
  const float* Wp1 = (const float*)d_in[8];
  const float* Wx2 = (const float*)d_in[9];
  const float* Wh2 = (const float*)d_in[10];
  const float* b2  = (const float*)d_in[11];
  const float* Wp2 = (const float*)d_in[12];
  const float* W   = (const float*)d_in[13];
  const float* lb  = (const float*)d_in[14];

  char* w = (char*)d_ws;
  auto take = [&](size_t bytes) { char* p = w; w += (bytes + 255) & ~(size_t)255; return p; };
  short* xb    = (short*)take((size_t)TT * NB * IIP * 2);   // 19.7 MB
  short* B0w   = (short*)take((size_t)G4 * 864 * 2);        //  5.3 MB
  short* B1w   = (short*)take((size_t)G4 * 1024 * 2);       //  6.3 MB
  short* B2w   = (short*)take((size_t)G4 * 1024 * 2);       //  6.3 MB
  float* pbw   = (float*)take((size_t)3 * G4 * 4);
  short* WpT0  = (short*)take((size_t)PP * HH * 2);
  short* WpT1  = (short*)take((size_t)PP * HH * 2);
  short* WhT1  = (short*)take((size_t)G4 * PP * 2);
  short* WhT2  = (short*)take((size_t)G4 * PP * 2);
  short* U     = (short*)take((size_t)2 * NB * HH * 2);
  short* seqH  = (short*)take((size_t)TT * NB * PP * 2);    // 52.4 MB (shared, in-place for layer 1)
  float* xg0b  = (float*)take((size_t)NB * G4 * 4);         //  3.1 MB
  float* Cw    = (float*)take((size_t)NB * HH * 4);         //  0.8 MB
  float* Sw    = (float*)take((size_t)NB * HH * 4);
  float* mhw   = (float*)take((size_t)NB * PP * 4);
  float* Wtw   = (float*)take((size_t)PP * PP * 4);
  // total ~98.8 MB of d_ws

  hipMemsetAsync(xb, 0, (size_t)TT * NB * IIP * 2, stream);
  hipMemsetAsync(Cw, 0, (size_t)NB * HH * 4, stream);
  hipMemsetAsync(Sw, 0, (size_t)NB * HH * 4, stream);

  k_xb<<<(TT * NB * 80 + 255) / 256, 256, 0, stream>>>(x, xb);
  k_makeB<<<dim3(12, 864), 256, 0, stream>>>(Wx0, Wp0, Wh0, B0w, 864, 96, 80);
  k_makeB<<<dim3(12, 1024), 256, 0, stream>>>(Wx1, Wp1, Wh1, B1w, 1024, 256, 256);
  k_makeB<<<dim3(12, 1024), 256, 0, stream>>>(Wx2, Wp2, Wh2, B2w, 1024, 256, 256);
  k_wpT<<<(PP * HH + 255) / 256, 256, 0, stream>>>(Wp0, WpT0);
  k_wpT<<<(PP * HH + 255) / 256, 256, 0, stream>>>(Wp1, WpT1);
  k_whT<<<(G4 * PP + 255) / 256, 256, 0, stream>>>(Wh1, WhT1);
  k_whT<<<(G4 * PP + 255) / 256, 256, 0, stream>>>(Wh2, WhT2);
  k_pb<<<(3 * G4 + 255) / 256, 256, 0, stream>>>(b0, b1, b2, pbw);
  k_wt<<<(PP * PP) / 256, 256, 0, stream>>>(W, Wtw);

  // ---- layer 0: input xb (stride 96, K=864), proj -> seqH ----
  for (int t = 0; t <= TT; ++t)
    k_step<864, 3><<<96, 256, 0, stream>>>(B0w, xb, IIP, WpT0, seqH, pbw + 0 * G4,
                                           U, Cw, Sw, xg0b, t, 0, 0);
  k_trans<<<96, 256, 0, stream>>>(seqH + (size_t)399 * NB * PP, WhT1, xg0b);

  // ---- layer 1: input seqH (stride 256, K=1024), proj -> seqH in-place ----
  for (int t = 0; t <= TT; ++t)
    k_step<1024, 8><<<96, 256, 0, stream>>>(B1w, seqH, PP, WpT1, seqH, pbw + 1 * G4,
                                            U, Cw, Sw, xg0b, t, 1, 0);
  k_trans<<<96, 256, 0, stream>>>(seqH + (size_t)399 * NB * PP, WhT2, xg0b);

  // ---- layer 2: input seqH, no proj, accumulate S ----
  for (int t = 0; t < TT; ++t)
    k_step<1024, 8><<<96, 256, 0, stream>>>(B2w, seqH, PP, nullptr, nullptr, pbw + 2 * G4,
                                            U, Cw, Sw, xg0b, t, 1, 1);

  k_mh<<<NB, 256, 0, stream>>>(Sw, Wp2, mhw);
  k_out<<<NB, 256, 0, stream>>>(mhw, Wtw, lb, (float*)d_out);
}